// Round 12
// baseline (118.002 us; speedup 1.0000x reference)
//
#include <hip/hip_runtime.h>

// Fused MHA: x->QKV proj (bf16 MFMA) -> causal flash attn -> O proj.
// B=2, T=2048, D=1024, H=16, HD=64.
// Round 12: r10 base (r11's complementary-ip reverted) +
//  - attn: single barrier per KV iter (WAITVM(2) -> BAR -> stage -> compute)
//  - k_gemm_out: 128x128 tiles, grid 256, XCD decode, direct f32 epilogue.

#define DEV __device__ __forceinline__

typedef __attribute__((ext_vector_type(8))) __bf16 bf16x8;
typedef __attribute__((ext_vector_type(4))) float f32x4;

DEV unsigned short f2bf(float f) {
  union { float f; unsigned u; } c;
  c.f = f;
  unsigned u = c.u + 0x7FFFu + ((c.u >> 16) & 1u);  // RTNE
  return (unsigned short)(u >> 16);
}

DEV unsigned cvtpk(float lo, float hi) {
  unsigned r;
  asm("v_cvt_pk_bf16_f32 %0, %1, %2" : "=v"(r) : "v"(lo), "v"(hi));
  return r;
}

DEV void gload16(const unsigned short* g, unsigned short* l) {
  __builtin_amdgcn_global_load_lds(
      (const __attribute__((address_space(1))) unsigned int*)g,
      (__attribute__((address_space(3))) unsigned int*)l, 16, 0, 0);
}

DEV f32x4 mfma16(bf16x8 a, bf16x8 b, f32x4 c) {
  return __builtin_amdgcn_mfma_f32_16x16x32_bf16(a, b, c, 0, 0, 0);
}

#define WAITVM(n) asm volatile("s_waitcnt vmcnt(" #n ")" ::: "memory")
#define WAITLGKM() asm volatile("s_waitcnt lgkmcnt(0)" ::: "memory")
#define BAR() __builtin_amdgcn_s_barrier()
#define SCHEDB() __builtin_amdgcn_sched_barrier(0)
#define PRIO(n) __builtin_amdgcn_s_setprio(n)

// ---------------- fp32 -> bf16 convert (all 5 tensors, one launch) -------
__global__ __launch_bounds__(256) void k_cvt_all(
    const float* __restrict__ x, const float* __restrict__ wq,
    const float* __restrict__ wk, const float* __restrict__ wv,
    const float* __restrict__ wo, unsigned short* __restrict__ dst) {
  int i = blockIdx.x * blockDim.x + threadIdx.x;  // float4 index
  const float* s;
  int off;
  if (i < 1048576) {
    s = x; off = i;
  } else {
    int j = i - 1048576;
    int w = j >> 18;
    off = j & 262143;
    s = (w == 0) ? wq : (w == 1) ? wk : (w == 2) ? wv : wo;
  }
  float4 v = reinterpret_cast<const float4*>(s)[off];
  uint2 o;
  o.x = (unsigned)f2bf(v.x) | ((unsigned)f2bf(v.y) << 16);
  o.y = (unsigned)f2bf(v.z) | ((unsigned)f2bf(v.w) << 16);
  reinterpret_cast<uint2*>(dst)[i] = o;
}

// ---------------- 128x128 bf16 GEMM core (C = A * W^T), K=1024 ----------
DEV void gemm_stage(const unsigned short* __restrict__ A,
                    const unsigned short* __restrict__ W,
                    unsigned short* la, unsigned short* lb,
                    int m0, int n0, int k0, int tid) {
#pragma unroll
  for (int i = 0; i < 2; ++i) {
    const int c = i * 256 + tid;
    const int row = c >> 2;
    const int scb = (((c & 3) << 4)) ^ ((row & 3) << 4);
    gload16(A + (m0 + row) * 1024 + k0 + (scb >> 1),
            (unsigned short*)((char*)la + c * 16));
    gload16(W + (n0 + row) * 1024 + k0 + (scb >> 1),
            (unsigned short*)((char*)lb + c * 16));
  }
}

DEV void gemm_core_128(const unsigned short* __restrict__ A,
                       const unsigned short* __restrict__ W,
                       unsigned short* la0, unsigned short* lb0,
                       int m0, int n0, f32x4 (&acc)[4][4]) {
  const int tid = threadIdx.x;
  const int lane = tid & 63;
  const int wave = tid >> 6;
  const int wm = (wave >> 1) * 64, wn = (wave & 1) * 64;
  const int g16 = ((lane >> 4) << 4);
  const int sx = (lane & 3) << 4;  // read-side swizzle (row&3 == lane&3)

  gemm_stage(A, W, la0, lb0, m0, n0, 0, tid);
  __syncthreads();

  for (int kt = 0; kt < 32; ++kt) {
    const int cur = kt & 1;
    unsigned short* la = la0 + cur * 4096;
    unsigned short* lb = lb0 + cur * 4096;
    if (kt + 1 < 32)
      gemm_stage(A, W, la0 + (cur ^ 1) * 4096, lb0 + (cur ^ 1) * 4096, m0, n0,
                 (kt + 1) * 32, tid);
    bf16x8 af[4], bfr[4];
#pragma unroll
    for (int m = 0; m < 4; ++m)
      af[m] = *reinterpret_cast<const bf16x8*>(
          (char*)la + (wm + m * 16 + (lane & 15)) * 64 + (g16 ^ sx));
#pragma unroll
    for (int n = 0; n < 4; ++n)
      bfr[n] = *reinterpret_cast<const bf16x8*>(
          (char*)lb + (wn + n * 16 + (lane & 15)) * 64 + (g16 ^ sx));
#pragma unroll
    for (int m = 0; m < 4; ++m)
#pragma unroll
      for (int n = 0; n < 4; ++n)
        acc[m][n] = mfma16(af[m], bfr[n], acc[m][n]);
    __syncthreads();
  }
}

// ---------------- QKV projection ----------------
// grid: 768 1-D. XCD co-location: xcd = (y&3)*2 + (x&1).
__global__ __launch_bounds__(256) void k_gemm_qkv(
    const unsigned short* __restrict__ X, const unsigned short* __restrict__ Wq,
    const unsigned short* __restrict__ Wk, const unsigned short* __restrict__ Wv,
    const float* __restrict__ bq, const float* __restrict__ bk,
    const float* __restrict__ bv, unsigned short* __restrict__ Qo,
    unsigned short* __restrict__ Ko, unsigned short* __restrict__ Vo) {
  __shared__ unsigned short ls[16384];  // la 2x4096 | lb 2x4096 (32 KB)
  const int id = blockIdx.x;
  const int xcd = id & 7, s4 = id >> 3;       // s4: 0..95
  const int mode = s4 >> 5;                   // z
  const int bx = ((s4 >> 3) & 3) * 2 + (xcd & 1);  // 0..7
  const int by = (s4 & 7) * 4 + (xcd >> 1);        // 0..31
  const unsigned short* W = (mode == 0) ? Wq : (mode == 1) ? Wk : Wv;
  const float* bias = (mode == 0) ? bq : (mode == 1) ? bk : bv;
  const int m0 = by * 128, n0 = bx * 128;
  f32x4 acc[4][4] = {};
  gemm_core_128(X, W, ls, ls + 8192, m0, n0, acc);

  const int lane = threadIdx.x & 63, wave = threadIdx.x >> 6;
  const int l15 = lane & 15, g = lane >> 4;
  const int wm = (wave >> 1) * 64, wn = (wave & 1) * 64;
  unsigned short* lw = ls + wave * 4096;  // per-wave 8KB region

  const int h = (n0 + wn) >> 6;
  const int rbase0 = m0 + wm;
  const int b = rbase0 >> 11;
  const int tb0 = rbase0 & 2047;

  if (mode == 2) {
    // V^T: LDS tile [hd 64][t 64], 8B-block-swizzled rows
#pragma unroll
    for (int m = 0; m < 4; ++m)
#pragma unroll
      for (int n = 0; n < 4; ++n) {
        const float bb = bias[n0 + wn + n * 16 + l15];
        uint2 w;
        w.x = cvtpk(acc[m][n][0] + bb, acc[m][n][1] + bb);
        w.y = cvtpk(acc[m][n][2] + bb, acc[m][n][3] + bb);
        *reinterpret_cast<uint2*>(
            (char*)lw + (n * 16 + l15) * 128 +
            ((((m << 2) + g) ^ (l15 & 14)) << 3)) = w;
      }
    WAITLGKM();
    SCHEDB();
#pragma unroll
    for (int it = 0; it < 8; ++it) {
      const int hd = (lane >> 3) + it * 8;
      const int jj = ((lane & 7) << 1) ^ (hd & 14);
      uint4 v = *reinterpret_cast<const uint4*>((char*)lw + hd * 128 + jj * 8);
      *reinterpret_cast<uint4*>(
          &Vo[((((b << 4) + h) << 6) + hd) * 2048 + tb0 + ((lane & 7) << 3)]) =
          v;
    }
  } else {
    // Q/K: LDS tile [t 64][hd 64]
    const float sc = (mode == 0) ? 0.180336880f : 1.0f;  // 0.125*log2(e)
#pragma unroll
    for (int m = 0; m < 4; ++m)
#pragma unroll
      for (int n = 0; n < 4; ++n) {
        const float bb = bias[n0 + wn + n * 16 + l15];
#pragma unroll
        for (int r = 0; r < 4; ++r)
          lw[(m * 16 + (g << 2) + r) * 64 + n * 16 + l15] =
              f2bf((acc[m][n][r] + bb) * sc);
      }
    WAITLGKM();
    SCHEDB();
    unsigned short* dst = (mode == 0) ? Qo : Ko;
#pragma unroll
    for (int it = 0; it < 8; ++it) {
      const int rr = (lane >> 3) + it * 8;
      const int ck = (lane & 7) * 8;
      uint4 v = *reinterpret_cast<const uint4*>(&lw[rr * 64 + ck]);
      *reinterpret_cast<uint4*>(
          &dst[(((b << 4) + h) * 2048 + tb0 + rr) * 64 + ck]) = v;
    }
  }
}

// ---------------- output projection (128x128 tiles, fp32 out + bias) -----
// grid: 256 1-D. xcd = (by&3)*2 + (bx&1).
__global__ __launch_bounds__(256) void k_gemm_out(
    const unsigned short* __restrict__ Ctx, const unsigned short* __restrict__ Wo,
    const float* __restrict__ bo, float* __restrict__ Out) {
  __shared__ unsigned short ls[16384];
  const int id = blockIdx.x;                       // 0..255
  const int xcd = id & 7, s4 = id >> 3;            // s4: 0..31
  const int bx = ((s4 >> 3) & 3) * 2 + (xcd & 1);  // 0..7
  const int by = (s4 & 7) * 4 + (xcd >> 1);        // 0..31
  const int m0 = by * 128, n0 = bx * 128;
  f32x4 acc[4][4] = {};
  gemm_core_128(Ctx, Wo, ls, ls + 8192, m0, n0, acc);

  const int lane = threadIdx.x & 63, wave = threadIdx.x >> 6;
  const int l15 = lane & 15, g = lane >> 4;
  const int wm = (wave >> 1) * 64, wn = (wave & 1) * 64;
#pragma unroll
  for (int m = 0; m < 4; ++m) {
    const int rbase = m0 + wm + m * 16 + (g << 2);
#pragma unroll
    for (int n = 0; n < 4; ++n) {
      const int col = n0 + wn + n * 16 + l15;
      const float bb = bo[col];
#pragma unroll
      for (int r = 0; r < 4; ++r)
        Out[(rbase + r) * 1024 + col] = acc[m][n][r] + bb;
    }
  }
}

// ---------------- causal flash attention (8-wave split-pair) -------------
// grid: 512 1-D with xcd = bh%8 (all 16 pair-blocks of a bh on one XCD).
// Single barrier per KV iter: WAITVM(2) -> BAR -> stage(t+2) -> compute(t).
// Safety: BAR(t) implies all waves finished compute(t-1) (their ds_reads
// completed via lgkm waits before MFMA consumers), so staging into
// buf[(t+2)%3] == buf[(t-1)%3] after BAR is hazard-free. WAITVM(2) drains
// only the oldest stage (tile t); tile t+1 stays in flight.

DEV void attn_stage(const unsigned short* __restrict__ Kb,
                    const unsigned short* __restrict__ Vb,
                    unsigned short* lk, unsigned short* lv, int kv0, int tid) {
  const int c = tid;              // 0..511 chunks of 16B
  const int row = c >> 3;
  const int cb = (c & 7) << 4;
  const int scb = cb ^ ((row & 7) << 4);  // pre-swizzle global source
  gload16(Kb + (kv0 + row) * 64 + (scb >> 1),
          (unsigned short*)((char*)lk + c * 16));
  gload16(Vb + row * 2048 + kv0 + (scb >> 1),
          (unsigned short*)((char*)lv + c * 16));
}

DEV void attn_step(const unsigned short* lk, const unsigned short* lv,
                   unsigned short (&lp)[16][72], const bf16x8 (&qf)[2],
                   f32x4 (&o)[4], float& lsum, int lane, int qloc, bool diag) {
  const int g = lane >> 4;
  f32x4 st[4];
  PRIO(1);
#pragma unroll
  for (int n = 0; n < 4; ++n) {
    f32x4 z = {};
    const int row = n * 16 + (lane & 15);
    const int sw = (row & 7) << 4;
#pragma unroll
    for (int kk = 0; kk < 2; ++kk) {
      bf16x8 kf = *reinterpret_cast<const bf16x8*>(
          (char*)lk + row * 128 + ((kk * 64 + (g << 4)) ^ sw));
      z = mfma16(kf, qf[kk], z);
    }
    st[n] = z;
  }
  PRIO(0);
  if (diag) {
#pragma unroll
    for (int n = 0; n < 4; ++n)
#pragma unroll
      for (int r = 0; r < 4; ++r)
        if (n * 16 + g * 4 + r > qloc) st[n][r] = -1e30f;
  }
  float rs = 0.f;
#pragma unroll
  for (int n = 0; n < 4; ++n)
#pragma unroll
    for (int r = 0; r < 4; ++r) {
      float p = exp2f(st[n][r]);
      st[n][r] = p;
      rs += p;
    }
  lsum += rs;
#pragma unroll
  for (int n = 0; n < 4; ++n) {
    uint2 w;
    w.x = cvtpk(st[n][0], st[n][1]);
    w.y = cvtpk(st[n][2], st[n][3]);
    *reinterpret_cast<uint2*>(&lp[lane & 15][n * 16 + g * 4]) = w;
  }
  WAITLGKM();
  SCHEDB();
  bf16x8 pb[2];
  pb[0] = *reinterpret_cast<const bf16x8*>(&lp[lane & 15][g * 8]);
  pb[1] = *reinterpret_cast<const bf16x8*>(&lp[lane & 15][32 + g * 8]);
  PRIO(1);
#pragma unroll
  for (int h = 0; h < 4; ++h) {
    const int row = h * 16 + (lane & 15);
    const int sw = (row & 7) << 4;
#pragma unroll
    for (int kk = 0; kk < 2; ++kk) {
      bf16x8 vf = *reinterpret_cast<const bf16x8*>(
          (char*)lv + row * 128 + ((kk * 64 + (g << 4)) ^ sw));
      o[h] = mfma16(vf, pb[kk], o[h]);
    }
  }
  PRIO(0);
}

DEV void attn_epi(unsigned short* __restrict__ Ctx,
                  unsigned short (&lp)[16][72], const f32x4 (&o)[4],
                  float lsum, int b, int hh, int qbase, int lane) {
  float lt = lsum;
  lt += __shfl_xor(lt, 16);
  lt += __shfl_xor(lt, 32);
  const float inv = 1.f / lt;
  const int g = lane >> 4;
#pragma unroll
  for (int h = 0; h < 4; ++h) {
    uint2 w;
    w.x = cvtpk(o[h][0] * inv, o[h][1] * inv);
    w.y = cvtpk(o[h][2] * inv, o[h][3] * inv);
    *reinterpret_cast<uint2*>(&lp[lane & 15][h * 16 + g * 4]) = w;
  }
  WAITLGKM();
  SCHEDB();
#pragma unroll
  for (int it = 0; it < 2; ++it) {
    const int q = (lane >> 3) + it * 8;
    const int ck = (lane & 7) * 8;
    uint4 v = *reinterpret_cast<const uint4*>(&lp[q][ck]);
    *reinterpret_cast<uint4*>(
        &Ctx[(b * 2048 + qbase + q) * 1024 + hh * 64 + ck]) = v;
  }
}

__global__ __launch_bounds__(512) void k_attn(
    const unsigned short* __restrict__ Q, const unsigned short* __restrict__ K,
    const unsigned short* __restrict__ Vt, unsigned short* __restrict__ Ctx) {
  __shared__ unsigned short lk[3 * 4096];   // K tiles, mod-3 cycle
  __shared__ unsigned short lv[3 * 4096];   // V tiles, mod-3 cycle
  __shared__ unsigned short lp[8][16][72];  // per-wave

  const int tid = threadIdx.x, lane = tid & 63, wave = tid >> 6;
  // XCD decode: xcd = bh%8 -> all pair-blocks of a bh on same XCD (r10).
  const int id = blockIdx.x;
  const int xcd = id & 7, r4 = id >> 3;  // r4: 0..63
  const int ip = r4 & 15;
  const int bh = ((r4 >> 4) << 3) + xcd;

  const int qtA = ip;          // small q-tile (qtA+1 kv tiles)
  const int qtB = 31 - ip;     // large q-tile
  const int nt = qtB + 1;      // >= 17

  const bool isB = wave < 4;
  const int wv4 = wave & 3;
  const int qt = isB ? qtB : qtA;
  const int myNt = isB ? nt : qtA + 1;  // # of active compute steps

  const unsigned short* Kb = K + bh * 2048 * 64;
  const unsigned short* Vb = Vt + bh * 64 * 2048;

  bf16x8 qf[2];
  {
    const unsigned short* qr =
        Q + (bh * 2048 + qt * 64 + wv4 * 16 + (lane & 15)) * 64 +
        ((lane >> 4) << 3);
    qf[0] = *reinterpret_cast<const bf16x8*>(qr);
    qf[1] = *reinterpret_cast<const bf16x8*>(qr + 32);
  }

  f32x4 o[4] = {};
  float lsum = 0.f;
  const int qloc = wv4 * 16 + (lane & 15);  // q within 64-row tile

  attn_stage(Kb, Vb, lk, lv, 0, tid);
  attn_stage(Kb, Vb, lk + 4096, lv + 4096, 64, tid);

  for (int t = 0; t < nt; ++t) {
    WAITVM(2);  // oldest stage (tile t) landed; tile t+1 stays in flight
    BAR();      // all waves: compute(t-1) fully done, tile t visible
    {
      const int nx = (t + 2 < nt) ? t + 2 : nt - 1;  // clamp: redundant stage
      attn_stage(Kb, Vb, lk + ((t + 2) % 3) * 4096, lv + ((t + 2) % 3) * 4096,
                 nx * 64, tid);
    }
    SCHEDB();
    if (t < myNt)
      attn_step(lk + (t % 3) * 4096, lv + (t % 3) * 4096, lp[wave], qf, o,
                lsum, lane, qloc, t == qt);
  }

  // Drain all in-flight global_load_lds before workgroup exit (LDS is
  // reallocated at endpgm; late DMA would corrupt the next workgroup).
  WAITVM(0);

  const int b = bh >> 4, hh = bh & 15;
  attn_epi(Ctx, lp[wave], o, lsum, b, hh, qt * 64 + wv4 * 16, lane);
}

// ---------------- launch ----------------
extern "C" void kernel_launch(void* const* d_in, const int* in_sizes, int n_in,
                              void* d_out, int out_size, void* d_ws,
                              size_t ws_size, hipStream_t stream) {
  const float* x = (const float*)d_in[0];
  const float* Wq = (const float*)d_in[1];
  const float* bq = (const float*)d_in[2];
  const float* Wk = (const float*)d_in[3];
  const float* bk = (const float*)d_in[4];
  const float* Wv = (const float*)d_in[5];
  const float* bv = (const float*)d_in[6];
  const float* Wo = (const float*)d_in[7];
  const float* bo = (const float*)d_in[8];
  float* out = (float*)d_out;

  char* ws = (char*)d_ws;
  unsigned short* xb = (unsigned short*)(ws);                    // 8 MB
  unsigned short* wqb = (unsigned short*)(ws + (8u << 20));      // 2 MB
  unsigned short* wkb = (unsigned short*)(ws + (10u << 20));
  unsigned short* wvb = (unsigned short*)(ws + (12u << 20));
  unsigned short* wob = (unsigned short*)(ws + (14u << 20));
  unsigned short* Qb = (unsigned short*)(ws + (16u << 20));      // 8 MB
  unsigned short* Kb = (unsigned short*)(ws + (24u << 20));      // 8 MB
  unsigned short* Vtb = (unsigned short*)(ws + (32u << 20));     // 8 MB
  unsigned short* Ctx = (unsigned short*)(ws + (40u << 20));     // 8 MB

  k_cvt_all<<<8192, 256, 0, stream>>>(x, Wq, Wk, Wv, Wo, xb);

  k_gemm_qkv<<<768, 256, 0, stream>>>(xb, wqb, wkb, wvb, bq, bk, bv,
                                      Qb, Kb, Vtb);
  k_attn<<<512, 512, 0, stream>>>(Qb, Kb, Vtb, Ctx);
  k_gemm_out<<<256, 256, 0, stream>>>(Ctx, wob, bo, out);
}

// Round 13
// 110.666 us; speedup vs baseline: 1.0663x; 1.0663x over previous
//
#include <hip/hip_runtime.h>

// Fused MHA: x->QKV proj (bf16 MFMA) -> causal flash attn -> O proj.
// B=2, T=2048, D=1024, H=16, HD=64.
// Round 13: k_gemm_out reverted to r10 (128x64, grid 512).
// attn: KVBLK=128, depth-1 double buffer, ONE barrier + ONE vmcnt(0) per
// 128 kv (L2-resident K/V make the full drain cheap). lp un-padded [16][64]
// with XOR-block swizzle -> LDS exactly 80KB, 2 blocks/CU.

#define DEV __device__ __forceinline__

typedef __attribute__((ext_vector_type(8))) __bf16 bf16x8;
typedef __attribute__((ext_vector_type(4))) float f32x4;

DEV unsigned short f2bf(float f) {
  union { float f; unsigned u; } c;
  c.f = f;
  unsigned u = c.u + 0x7FFFu + ((c.u >> 16) & 1u);  // RTNE
  return (unsigned short)(u >> 16);
}

DEV unsigned cvtpk(float lo, float hi) {
  unsigned r;
  asm("v_cvt_pk_bf16_f32 %0, %1, %2" : "=v"(r) : "v"(lo), "v"(hi));
  return r;
}

DEV void gload16(const unsigned short* g, unsigned short* l) {
  __builtin_amdgcn_global_load_lds(
      (const __attribute__((address_space(1))) unsigned int*)g,
      (__attribute__((address_space(3))) unsigned int*)l, 16, 0, 0);
}

DEV f32x4 mfma16(bf16x8 a, bf16x8 b, f32x4 c) {
  return __builtin_amdgcn_mfma_f32_16x16x32_bf16(a, b, c, 0, 0, 0);
}

#define WAITVM(n) asm volatile("s_waitcnt vmcnt(" #n ")" ::: "memory")
#define WAITLGKM() asm volatile("s_waitcnt lgkmcnt(0)" ::: "memory")
#define BAR() __builtin_amdgcn_s_barrier()
#define SCHEDB() __builtin_amdgcn_sched_barrier(0)
#define PRIO(n) __builtin_amdgcn_s_setprio(n)

// ---------------- fp32 -> bf16 convert (all 5 tensors, one launch) -------
__global__ __launch_bounds__(256) void k_cvt_all(
    const float* __restrict__ x, const float* __restrict__ wq,
    const float* __restrict__ wk, const float* __restrict__ wv,
    const float* __restrict__ wo, unsigned short* __restrict__ dst) {
  int i = blockIdx.x * blockDim.x + threadIdx.x;  // float4 index
  const float* s;
  int off;
  if (i < 1048576) {
    s = x; off = i;
  } else {
    int j = i - 1048576;
    int w = j >> 18;
    off = j & 262143;
    s = (w == 0) ? wq : (w == 1) ? wk : (w == 2) ? wv : wo;
  }
  float4 v = reinterpret_cast<const float4*>(s)[off];
  uint2 o;
  o.x = (unsigned)f2bf(v.x) | ((unsigned)f2bf(v.y) << 16);
  o.y = (unsigned)f2bf(v.z) | ((unsigned)f2bf(v.w) << 16);
  reinterpret_cast<uint2*>(dst)[i] = o;
}

// ---------------- 128x128 bf16 GEMM core (C = A * W^T), K=1024 ----------
DEV void gemm_stage(const unsigned short* __restrict__ A,
                    const unsigned short* __restrict__ W,
                    unsigned short* la, unsigned short* lb,
                    int m0, int n0, int k0, int tid) {
#pragma unroll
  for (int i = 0; i < 2; ++i) {
    const int c = i * 256 + tid;
    const int row = c >> 2;
    const int scb = (((c & 3) << 4)) ^ ((row & 3) << 4);
    gload16(A + (m0 + row) * 1024 + k0 + (scb >> 1),
            (unsigned short*)((char*)la + c * 16));
    gload16(W + (n0 + row) * 1024 + k0 + (scb >> 1),
            (unsigned short*)((char*)lb + c * 16));
  }
}

DEV void gemm_core_128(const unsigned short* __restrict__ A,
                       const unsigned short* __restrict__ W,
                       unsigned short* la0, unsigned short* lb0,
                       int m0, int n0, f32x4 (&acc)[4][4]) {
  const int tid = threadIdx.x;
  const int lane = tid & 63;
  const int wave = tid >> 6;
  const int wm = (wave >> 1) * 64, wn = (wave & 1) * 64;
  const int g16 = ((lane >> 4) << 4);
  const int sx = (lane & 3) << 4;  // read-side swizzle (row&3 == lane&3)

  gemm_stage(A, W, la0, lb0, m0, n0, 0, tid);
  __syncthreads();

  for (int kt = 0; kt < 32; ++kt) {
    const int cur = kt & 1;
    unsigned short* la = la0 + cur * 4096;
    unsigned short* lb = lb0 + cur * 4096;
    if (kt + 1 < 32)
      gemm_stage(A, W, la0 + (cur ^ 1) * 4096, lb0 + (cur ^ 1) * 4096, m0, n0,
                 (kt + 1) * 32, tid);
    bf16x8 af[4], bfr[4];
#pragma unroll
    for (int m = 0; m < 4; ++m)
      af[m] = *reinterpret_cast<const bf16x8*>(
          (char*)la + (wm + m * 16 + (lane & 15)) * 64 + (g16 ^ sx));
#pragma unroll
    for (int n = 0; n < 4; ++n)
      bfr[n] = *reinterpret_cast<const bf16x8*>(
          (char*)lb + (wn + n * 16 + (lane & 15)) * 64 + (g16 ^ sx));
#pragma unroll
    for (int m = 0; m < 4; ++m)
#pragma unroll
      for (int n = 0; n < 4; ++n)
        acc[m][n] = mfma16(af[m], bfr[n], acc[m][n]);
    __syncthreads();
  }
}

// ---------------- QKV projection ----------------
// grid: 768 1-D. XCD co-location: xcd = (y&3)*2 + (x&1).
__global__ __launch_bounds__(256) void k_gemm_qkv(
    const unsigned short* __restrict__ X, const unsigned short* __restrict__ Wq,
    const unsigned short* __restrict__ Wk, const unsigned short* __restrict__ Wv,
    const float* __restrict__ bq, const float* __restrict__ bk,
    const float* __restrict__ bv, unsigned short* __restrict__ Qo,
    unsigned short* __restrict__ Ko, unsigned short* __restrict__ Vo) {
  __shared__ unsigned short ls[16384];  // la 2x4096 | lb 2x4096 (32 KB)
  const int id = blockIdx.x;
  const int xcd = id & 7, s4 = id >> 3;       // s4: 0..95
  const int mode = s4 >> 5;                   // z
  const int bx = ((s4 >> 3) & 3) * 2 + (xcd & 1);  // 0..7
  const int by = (s4 & 7) * 4 + (xcd >> 1);        // 0..31
  const unsigned short* W = (mode == 0) ? Wq : (mode == 1) ? Wk : Wv;
  const float* bias = (mode == 0) ? bq : (mode == 1) ? bk : bv;
  const int m0 = by * 128, n0 = bx * 128;
  f32x4 acc[4][4] = {};
  gemm_core_128(X, W, ls, ls + 8192, m0, n0, acc);

  const int lane = threadIdx.x & 63, wave = threadIdx.x >> 6;
  const int l15 = lane & 15, g = lane >> 4;
  const int wm = (wave >> 1) * 64, wn = (wave & 1) * 64;
  unsigned short* lw = ls + wave * 4096;  // per-wave 8KB region

  const int h = (n0 + wn) >> 6;
  const int rbase0 = m0 + wm;
  const int b = rbase0 >> 11;
  const int tb0 = rbase0 & 2047;

  if (mode == 2) {
    // V^T: LDS tile [hd 64][t 64], 8B-block-swizzled rows
#pragma unroll
    for (int m = 0; m < 4; ++m)
#pragma unroll
      for (int n = 0; n < 4; ++n) {
        const float bb = bias[n0 + wn + n * 16 + l15];
        uint2 w;
        w.x = cvtpk(acc[m][n][0] + bb, acc[m][n][1] + bb);
        w.y = cvtpk(acc[m][n][2] + bb, acc[m][n][3] + bb);
        *reinterpret_cast<uint2*>(
            (char*)lw + (n * 16 + l15) * 128 +
            ((((m << 2) + g) ^ (l15 & 14)) << 3)) = w;
      }
    WAITLGKM();
    SCHEDB();
#pragma unroll
    for (int it = 0; it < 8; ++it) {
      const int hd = (lane >> 3) + it * 8;
      const int jj = ((lane & 7) << 1) ^ (hd & 14);
      uint4 v = *reinterpret_cast<const uint4*>((char*)lw + hd * 128 + jj * 8);
      *reinterpret_cast<uint4*>(
          &Vo[((((b << 4) + h) << 6) + hd) * 2048 + tb0 + ((lane & 7) << 3)]) =
          v;
    }
  } else {
    // Q/K: LDS tile [t 64][hd 64]
    const float sc = (mode == 0) ? 0.180336880f : 1.0f;  // 0.125*log2(e)
#pragma unroll
    for (int m = 0; m < 4; ++m)
#pragma unroll
      for (int n = 0; n < 4; ++n) {
        const float bb = bias[n0 + wn + n * 16 + l15];
#pragma unroll
        for (int r = 0; r < 4; ++r)
          lw[(m * 16 + (g << 2) + r) * 64 + n * 16 + l15] =
              f2bf((acc[m][n][r] + bb) * sc);
      }
    WAITLGKM();
    SCHEDB();
    unsigned short* dst = (mode == 0) ? Qo : Ko;
#pragma unroll
    for (int it = 0; it < 8; ++it) {
      const int rr = (lane >> 3) + it * 8;
      const int ck = (lane & 7) * 8;
      uint4 v = *reinterpret_cast<const uint4*>(&lw[rr * 64 + ck]);
      *reinterpret_cast<uint4*>(
          &dst[(((b << 4) + h) * 2048 + tb0 + rr) * 64 + ck]) = v;
    }
  }
}

// ---------------- output projection (128x64 tiles, fp32 out + bias) ------
// grid: 512 1-D. xcd = (y&3)*2 + (x&1). (r10 version)
__global__ __launch_bounds__(256) void k_gemm_out(
    const unsigned short* __restrict__ Ctx, const unsigned short* __restrict__ Wo,
    const float* __restrict__ bo, float* __restrict__ Out) {
  __shared__ unsigned short ls[16384];
  unsigned short* la0 = ls;
  unsigned short* lb0 = ls + 8192;
  const int id = blockIdx.x;
  const int xcd = id & 7, s4 = id >> 3;            // s4: 0..63
  const int bx = ((s4 >> 3) & 7) * 2 + (xcd & 1);  // 0..15
  const int by = (s4 & 7) * 4 + (xcd >> 1);        // 0..31
  const int tid = threadIdx.x;
  const int lane = tid & 63, wave = tid >> 6;
  const int l15 = lane & 15, g = lane >> 4;
  const int m0 = by * 128, n0 = bx * 64;
  const int wm = (wave >> 1) * 64, wn = (wave & 1) * 32;
  const int g16 = (g << 4);
  const int sx = (lane & 3) << 4;
  f32x4 acc[4][2] = {};

#define STG_OUT(buf, k0)                                                     \
  {                                                                          \
    _Pragma("unroll") for (int i = 0; i < 2; ++i) {                          \
      const int c = i * 256 + tid;                                           \
      const int row = c >> 2;                                                \
      const int scb = (((c & 3) << 4)) ^ ((row & 3) << 4);                   \
      gload16(Ctx + (m0 + row) * 1024 + (k0) + (scb >> 1),                   \
              (unsigned short*)((char*)(la0 + (buf)*4096) + c * 16));        \
    }                                                                        \
    {                                                                        \
      const int row = tid >> 2;                                              \
      const int scb = (((tid & 3) << 4)) ^ ((row & 3) << 4);                 \
      gload16(Wo + (n0 + row) * 1024 + (k0) + (scb >> 1),                    \
              (unsigned short*)((char*)(lb0 + (buf)*2048) + tid * 16));      \
    }                                                                        \
  }

  STG_OUT(0, 0);
  __syncthreads();

  for (int kt = 0; kt < 32; ++kt) {
    const int cur = kt & 1;
    unsigned short* la = la0 + cur * 4096;
    unsigned short* lb = lb0 + cur * 2048;
    if (kt + 1 < 32) STG_OUT(cur ^ 1, (kt + 1) * 32);
    bf16x8 af[4], bfr[2];
#pragma unroll
    for (int m = 0; m < 4; ++m)
      af[m] = *reinterpret_cast<const bf16x8*>(
          (char*)la + (wm + m * 16 + l15) * 64 + (g16 ^ sx));
#pragma unroll
    for (int n = 0; n < 2; ++n)
      bfr[n] = *reinterpret_cast<const bf16x8*>(
          (char*)lb + (wn + n * 16 + l15) * 64 + (g16 ^ sx));
#pragma unroll
    for (int m = 0; m < 4; ++m)
#pragma unroll
      for (int n = 0; n < 2; ++n)
        acc[m][n] = mfma16(af[m], bfr[n], acc[m][n]);
    __syncthreads();
  }
#undef STG_OUT

  float* lwf = (float*)(ls + wave * 4096);
#pragma unroll
  for (int m = 0; m < 4; ++m)
#pragma unroll
    for (int n = 0; n < 2; ++n) {
      const float bb = bo[n0 + wn + n * 16 + l15];
#pragma unroll
      for (int r = 0; r < 4; ++r)
        lwf[(m * 16 + (g << 2) + r) * 32 + n * 16 + l15] = acc[m][n][r] + bb;
    }
  WAITLGKM();
  SCHEDB();
#pragma unroll
  for (int it = 0; it < 8; ++it) {
    const int rr = (lane >> 3) + it * 8;
    const int ck = (lane & 7) * 4;
    float4 v = *reinterpret_cast<const float4*>(&lwf[rr * 32 + ck]);
    *reinterpret_cast<float4*>(&Out[(m0 + wm + rr) * 1024 + n0 + wn + ck]) = v;
  }
}

// ---------------- causal flash attention (8-wave split-pair, KVBLK=128) --
// grid: 512 1-D, xcd = bh%8 (r10 decode). Per iter: ONE vmcnt(0) drain +
// ONE barrier, then 2 sub-steps of 64 kv. K tile [128][64] (128B rows),
// V^T tile [64][128] (256B rows), both XOR-swizzled via pre-swizzled
// global source. lp un-padded [16][64] with the same XOR-block swizzle.

DEV void attn_stage128(const unsigned short* __restrict__ Kb,
                       const unsigned short* __restrict__ Vb,
                       unsigned short* lk, unsigned short* lv, int kv0,
                       int tid) {
#pragma unroll
  for (int i = 0; i < 2; ++i) {
    const int c = i * 512 + tid;            // 0..1023 chunks of 16B
    const int krow = c >> 3;                // 0..127
    const int kscb = ((c & 7) << 4) ^ ((krow & 7) << 4);
    gload16(Kb + (kv0 + krow) * 64 + (kscb >> 1),
            (unsigned short*)((char*)lk + c * 16));
    const int vrow = c >> 4;                // hd 0..63
    const int vscb = ((c & 15) << 4) ^ ((vrow & 7) << 4);  // XOR bits 4-6
    gload16(Vb + vrow * 2048 + kv0 + (vscb >> 1),
            (unsigned short*)((char*)lv + c * 16));
  }
}

// one 64-kv sub-step; lk128 = 128-row K tile base, s = sub-tile (0/1),
// lv128 = V^T tile base (256B rows).
DEV void attn_step(const unsigned short* lk128, int s,
                   const unsigned short* lv128,
                   unsigned short (&lp)[16][64], const bf16x8 (&qf)[2],
                   f32x4 (&o)[4], float& lsum, int lane, int qloc, bool diag) {
  const int g = lane >> 4;
  const int l15 = lane & 15;
  f32x4 st[4];
  PRIO(1);
#pragma unroll
  for (int n = 0; n < 4; ++n) {
    f32x4 z = {};
    const int row = n * 16 + l15;           // row within sub-tile
    const int sw = (row & 7) << 4;
#pragma unroll
    for (int kk = 0; kk < 2; ++kk) {
      bf16x8 kf = *reinterpret_cast<const bf16x8*>(
          (char*)lk128 + (s * 64 + row) * 128 + ((kk * 64 + (g << 4)) ^ sw));
      z = mfma16(kf, qf[kk], z);
    }
    st[n] = z;
  }
  PRIO(0);
  if (diag) {
#pragma unroll
    for (int n = 0; n < 4; ++n)
#pragma unroll
      for (int r = 0; r < 4; ++r)
        if (n * 16 + g * 4 + r > qloc) st[n][r] = -1e30f;
  }
  float rs = 0.f;
#pragma unroll
  for (int n = 0; n < 4; ++n)
#pragma unroll
    for (int r = 0; r < 4; ++r) {
      float p = exp2f(st[n][r]);
      st[n][r] = p;
      rs += p;
    }
  lsum += rs;
  const int psw = (l15 & 7) << 4;
#pragma unroll
  for (int n = 0; n < 4; ++n) {
    uint2 w;
    w.x = cvtpk(st[n][0], st[n][1]);
    w.y = cvtpk(st[n][2], st[n][3]);
    *reinterpret_cast<uint2*>(
        (char*)lp + l15 * 128 + (((n << 5) | (g << 3)) ^ psw)) = w;
  }
  WAITLGKM();
  SCHEDB();
  bf16x8 pb[2];
  pb[0] = *reinterpret_cast<const bf16x8*>(
      (char*)lp + l15 * 128 + (((g << 4)) ^ psw));
  pb[1] = *reinterpret_cast<const bf16x8*>(
      (char*)lp + l15 * 128 + ((64 + (g << 4)) ^ psw));
  PRIO(1);
#pragma unroll
  for (int h = 0; h < 4; ++h) {
    const int vr = h * 16 + l15;            // hd row
    const int sw = (vr & 7) << 4;
#pragma unroll
    for (int kk = 0; kk < 2; ++kk) {
      bf16x8 vf = *reinterpret_cast<const bf16x8*>(
          (char*)lv128 + vr * 256 + ((s * 128 + kk * 64 + (g << 4)) ^ sw));
      o[h] = mfma16(vf, pb[kk], o[h]);
    }
  }
  PRIO(0);
}

DEV void attn_epi(unsigned short* __restrict__ Ctx,
                  unsigned short (&lp)[16][64], const f32x4 (&o)[4],
                  float lsum, int b, int hh, int qbase, int lane) {
  float lt = lsum;
  lt += __shfl_xor(lt, 16);
  lt += __shfl_xor(lt, 32);
  const float inv = 1.f / lt;
  const int g = lane >> 4;
  const int l15 = lane & 15;
  const int psw = (l15 & 7) << 4;
#pragma unroll
  for (int h = 0; h < 4; ++h) {
    uint2 w;
    w.x = cvtpk(o[h][0] * inv, o[h][1] * inv);
    w.y = cvtpk(o[h][2] * inv, o[h][3] * inv);
    *reinterpret_cast<uint2*>(
        (char*)lp + l15 * 128 + (((h << 5) | (g << 3)) ^ psw)) = w;
  }
  WAITLGKM();
  SCHEDB();
#pragma unroll
  for (int it = 0; it < 2; ++it) {
    const int q = (lane >> 3) + it * 8;
    const int blk = (lane & 7) ^ (q & 7);
    uint4 v = *reinterpret_cast<const uint4*>((char*)lp + q * 128 + blk * 16);
    *reinterpret_cast<uint4*>(
        &Ctx[(b * 2048 + qbase + q) * 1024 + hh * 64 + ((lane & 7) << 3)]) = v;
  }
}

__global__ __launch_bounds__(512) void k_attn(
    const unsigned short* __restrict__ Q, const unsigned short* __restrict__ K,
    const unsigned short* __restrict__ Vt, unsigned short* __restrict__ Ctx) {
  __shared__ unsigned short lk[2][8192];    // K [128][64], double buffer
  __shared__ unsigned short lv[2][8192];    // V^T [64][128], double buffer
  __shared__ unsigned short lp[8][16][64];  // per-wave, XOR-swizzled

  const int tid = threadIdx.x, lane = tid & 63, wave = tid >> 6;
  const int id = blockIdx.x;
  const int xcd = id & 7, r4 = id >> 3;  // r4: 0..63
  const int ip = r4 & 15;
  const int bh = ((r4 >> 4) << 3) + xcd;

  const int qtA = ip;          // small q-tile
  const int qtB = 31 - ip;     // large q-tile
  const int nb = (qtB >> 1) + 1;  // 128-kv blocks for B (9..16)

  const bool isB = wave < 4;
  const int wv4 = wave & 3;
  const int qt = isB ? qtB : qtA;

  const unsigned short* Kb = K + bh * 2048 * 64;
  const unsigned short* Vb = Vt + bh * 64 * 2048;

  bf16x8 qf[2];
  {
    const unsigned short* qr =
        Q + (bh * 2048 + qt * 64 + wv4 * 16 + (lane & 15)) * 64 +
        ((lane >> 4) << 3);
    qf[0] = *reinterpret_cast<const bf16x8*>(qr);
    qf[1] = *reinterpret_cast<const bf16x8*>(qr + 32);
  }

  f32x4 o[4] = {};
  float lsum = 0.f;
  const int qloc = wv4 * 16 + (lane & 15);  // q within 64-row tile

  attn_stage128(Kb, Vb, lk[0], lv[0], 0, tid);

  for (int t = 0; t < nb; ++t) {
    WAITVM(0);  // stage(t) fully landed (L2-resident, short drain)
    BAR();      // all waves done with compute(t-1); stage(t) visible
    {
      const int nx = (t + 1 < nb) ? t + 1 : nb - 1;  // clamp: redundant
      attn_stage128(Kb, Vb, lk[(t + 1) & 1], lv[(t + 1) & 1], nx * 128, tid);
    }
    SCHEDB();
    const unsigned short* lkc = lk[t & 1];
    const unsigned short* lvc = lv[t & 1];
#pragma unroll
    for (int s = 0; s < 2; ++s) {
      const int sub = 2 * t + s;
      if (sub <= qt)
        attn_step(lkc, s, lvc, lp[wave], qf, o, lsum, lane, qloc, sub == qt);
    }
  }

  // Drain all in-flight global_load_lds before workgroup exit (LDS is
  // reallocated at endpgm; late DMA would corrupt the next workgroup).
  WAITVM(0);

  const int b = bh >> 4, hh = bh & 15;
  attn_epi(Ctx, lp[wave], o, lsum, b, hh, qt * 64 + wv4 * 16, lane);
}

// ---------------- launch ----------------
extern "C" void kernel_launch(void* const* d_in, const int* in_sizes, int n_in,
                              void* d_out, int out_size, void* d_ws,
                              size_t ws_size, hipStream_t stream) {
  const float* x = (const float*)d_in[0];
  const float* Wq = (const float*)d_in[1];
  const float* bq = (const float*)d_in[2];
  const float* Wk = (const float*)d_in[3];
  const float* bk = (const float*)d_in[4];
  const float* Wv = (const float*)d_in[5];
  const float* bv = (const float*)d_in[6];
  const float* Wo = (const float*)d_in[7];
  const float* bo = (const float*)d_in[8];
  float* out = (float*)d_out;

  char* ws = (char*)d_ws;
  unsigned short* xb = (unsigned short*)(ws);                    // 8 MB
  unsigned short* wqb = (unsigned short*)(ws + (8u << 20));      // 2 MB
  unsigned short* wkb = (unsigned short*)(ws + (10u << 20));
  unsigned short* wvb = (unsigned short*)(ws + (12u << 20));
  unsigned short* wob = (unsigned short*)(ws + (14u << 20));
  unsigned short* Qb = (unsigned short*)(ws + (16u << 20));      // 8 MB
  unsigned short* Kb = (unsigned short*)(ws + (24u << 20));      // 8 MB
  unsigned short* Vtb = (unsigned short*)(ws + (32u << 20));     // 8 MB
  unsigned short* Ctx = (unsigned short*)(ws + (40u << 20));     // 8 MB

  k_cvt_all<<<8192, 256, 0, stream>>>(x, Wq, Wk, Wv, Wo, xb);

  k_gemm_qkv<<<768, 256, 0, stream>>>(xb, wqb, wkb, wvb, bq, bk, bv,
                                      Qb, Kb, Vtb);
  k_attn<<<512, 512, 0, stream>>>(Qb, Kb, Vtb, Ctx);
  k_gemm_out<<<512, 256, 0, stream>>>(Ctx, wob, bo, out);
}

// Round 14
// 106.808 us; speedup vs baseline: 1.1048x; 1.0361x over previous
//
#include <hip/hip_runtime.h>

// Fused MHA: x->QKV proj (bf16 MFMA) -> causal flash attn -> O proj.
// B=2, T=2048, D=1024, H=16, HD=64.
// Round 14: FUSED QKV — one block computes Q,K,V 128x64 tiles sharing the
// staged X tile (X staged once, not 3x). Grid 512 (2 blocks/CU), 40KB LDS,
// 24 MFMA/wave/iter. attn = r13 (KVBLK=128), out = r10, cvt unchanged.

#define DEV __device__ __forceinline__

typedef __attribute__((ext_vector_type(8))) __bf16 bf16x8;
typedef __attribute__((ext_vector_type(4))) float f32x4;

DEV unsigned short f2bf(float f) {
  union { float f; unsigned u; } c;
  c.f = f;
  unsigned u = c.u + 0x7FFFu + ((c.u >> 16) & 1u);  // RTNE
  return (unsigned short)(u >> 16);
}

DEV unsigned cvtpk(float lo, float hi) {
  unsigned r;
  asm("v_cvt_pk_bf16_f32 %0, %1, %2" : "=v"(r) : "v"(lo), "v"(hi));
  return r;
}

DEV void gload16(const unsigned short* g, unsigned short* l) {
  __builtin_amdgcn_global_load_lds(
      (const __attribute__((address_space(1))) unsigned int*)g,
      (__attribute__((address_space(3))) unsigned int*)l, 16, 0, 0);
}

DEV f32x4 mfma16(bf16x8 a, bf16x8 b, f32x4 c) {
  return __builtin_amdgcn_mfma_f32_16x16x32_bf16(a, b, c, 0, 0, 0);
}

#define WAITVM(n) asm volatile("s_waitcnt vmcnt(" #n ")" ::: "memory")
#define WAITLGKM() asm volatile("s_waitcnt lgkmcnt(0)" ::: "memory")
#define BAR() __builtin_amdgcn_s_barrier()
#define SCHEDB() __builtin_amdgcn_sched_barrier(0)
#define PRIO(n) __builtin_amdgcn_s_setprio(n)

// ---------------- fp32 -> bf16 convert (all 5 tensors, one launch) -------
__global__ __launch_bounds__(256) void k_cvt_all(
    const float* __restrict__ x, const float* __restrict__ wq,
    const float* __restrict__ wk, const float* __restrict__ wv,
    const float* __restrict__ wo, unsigned short* __restrict__ dst) {
  int i = blockIdx.x * blockDim.x + threadIdx.x;  // float4 index
  const float* s;
  int off;
  if (i < 1048576) {
    s = x; off = i;
  } else {
    int j = i - 1048576;
    int w = j >> 18;
    off = j & 262143;
    s = (w == 0) ? wq : (w == 1) ? wk : (w == 2) ? wv : wo;
  }
  float4 v = reinterpret_cast<const float4*>(s)[off];
  uint2 o;
  o.x = (unsigned)f2bf(v.x) | ((unsigned)f2bf(v.y) << 16);
  o.y = (unsigned)f2bf(v.z) | ((unsigned)f2bf(v.w) << 16);
  reinterpret_cast<uint2*>(dst)[i] = o;
}

// ---------------- FUSED QKV projection (128x64 tiles, 3 modes) ----------
// grid: 512 1-D. xcd = (by&3)*2 + (bx&1). X tile staged ONCE per K-iter,
// shared by Q/K/V MFMAs. Waves: wm=(w>>1)*64, wn=(w&1)*32.
__global__ __launch_bounds__(256) void k_gemm_qkv(
    const unsigned short* __restrict__ X, const unsigned short* __restrict__ Wq,
    const unsigned short* __restrict__ Wk, const unsigned short* __restrict__ Wv,
    const float* __restrict__ bq, const float* __restrict__ bk,
    const float* __restrict__ bv, unsigned short* __restrict__ Qo,
    unsigned short* __restrict__ Ko, unsigned short* __restrict__ Vo) {
  __shared__ unsigned short ls[20480];  // X 2x4096 | Wq 2x2048 | Wk | Wv
  unsigned short* la0 = ls;             // +buf*4096
  unsigned short* lbq = ls + 8192;      // +buf*2048
  unsigned short* lbk = ls + 12288;
  unsigned short* lbv = ls + 16384;

  const int id = blockIdx.x;
  const int xcd = id & 7, s4 = id >> 3;            // s4: 0..63
  const int bx = ((s4 >> 3) & 7) * 2 + (xcd & 1);  // 0..15
  const int by = (s4 & 7) * 4 + (xcd >> 1);        // 0..31
  const int m0 = by * 128, n0 = bx * 64;

  const int tid = threadIdx.x;
  const int lane = tid & 63, wave = tid >> 6;
  const int l15 = lane & 15, g = lane >> 4;
  const int wm = (wave >> 1) * 64, wn = (wave & 1) * 32;
  const int g16 = g << 4;
  const int sx = (lane & 3) << 4;

  f32x4 a0[4][2] = {}, a1[4][2] = {}, a2[4][2] = {};

#define STG_QKV(buf, k0)                                                     \
  {                                                                          \
    _Pragma("unroll") for (int i = 0; i < 2; ++i) {                          \
      const int c = i * 256 + tid;                                           \
      const int row = c >> 2;                                                \
      const int scb = ((c & 3) << 4) ^ ((row & 3) << 4);                     \
      gload16(X + (m0 + row) * 1024 + (k0) + (scb >> 1),                     \
              (unsigned short*)((char*)(la0 + (buf)*4096) + c * 16));        \
    }                                                                        \
    {                                                                        \
      const int row = tid >> 2;                                              \
      const int scb = ((tid & 3) << 4) ^ ((row & 3) << 4);                   \
      const int go = (n0 + row) * 1024 + (k0) + (scb >> 1);                  \
      gload16(Wq + go,                                                       \
              (unsigned short*)((char*)(lbq + (buf)*2048) + tid * 16));      \
      gload16(Wk + go,                                                       \
              (unsigned short*)((char*)(lbk + (buf)*2048) + tid * 16));      \
      gload16(Wv + go,                                                       \
              (unsigned short*)((char*)(lbv + (buf)*2048) + tid * 16));      \
    }                                                                        \
  }

  STG_QKV(0, 0);
  __syncthreads();

  for (int kt = 0; kt < 32; ++kt) {
    const int cur = kt & 1;
    if (kt + 1 < 32) STG_QKV(cur ^ 1, (kt + 1) * 32);
    unsigned short* la = la0 + cur * 4096;
    bf16x8 af[4];
#pragma unroll
    for (int m = 0; m < 4; ++m)
      af[m] = *reinterpret_cast<const bf16x8*>(
          (char*)la + (wm + m * 16 + l15) * 64 + (g16 ^ sx));
    {
      unsigned short* lb = lbq + cur * 2048;
      bf16x8 bfr[2];
#pragma unroll
      for (int n = 0; n < 2; ++n)
        bfr[n] = *reinterpret_cast<const bf16x8*>(
            (char*)lb + (wn + n * 16 + l15) * 64 + (g16 ^ sx));
#pragma unroll
      for (int m = 0; m < 4; ++m)
#pragma unroll
        for (int n = 0; n < 2; ++n) a0[m][n] = mfma16(af[m], bfr[n], a0[m][n]);
    }
    {
      unsigned short* lb = lbk + cur * 2048;
      bf16x8 bfr[2];
#pragma unroll
      for (int n = 0; n < 2; ++n)
        bfr[n] = *reinterpret_cast<const bf16x8*>(
            (char*)lb + (wn + n * 16 + l15) * 64 + (g16 ^ sx));
#pragma unroll
      for (int m = 0; m < 4; ++m)
#pragma unroll
        for (int n = 0; n < 2; ++n) a1[m][n] = mfma16(af[m], bfr[n], a1[m][n]);
    }
    {
      unsigned short* lb = lbv + cur * 2048;
      bf16x8 bfr[2];
#pragma unroll
      for (int n = 0; n < 2; ++n)
        bfr[n] = *reinterpret_cast<const bf16x8*>(
            (char*)lb + (wn + n * 16 + l15) * 64 + (g16 ^ sx));
#pragma unroll
      for (int m = 0; m < 4; ++m)
#pragma unroll
        for (int n = 0; n < 2; ++n) a2[m][n] = mfma16(af[m], bfr[n], a2[m][n]);
    }
    __syncthreads();
  }
#undef STG_QKV

  // ---- epilogues (per-wave 4KB lw; modes sequential with lgkm fences) ----
  unsigned short* lw = ls + wave * 2048;
  const int h = (n0 + wn) >> 6;
  const int hd0 = (n0 + wn) & 63;       // 0 or 32
  const int rb = m0 + wm;
  const int b = rb >> 11;
  const int tb0 = rb & 2047;

  // Q (scaled) then K: lw[64 t][32 hd]
#pragma unroll
  for (int mode = 0; mode < 2; ++mode) {
    const float* bias = mode ? bk : bq;
    const float sc = mode ? 1.0f : 0.180336880f;  // 0.125*log2(e)
    unsigned short* dst = mode ? Ko : Qo;
    WAITLGKM();  // prior mode's lw reads complete before overwrite
#pragma unroll
    for (int m = 0; m < 4; ++m)
#pragma unroll
      for (int n = 0; n < 2; ++n) {
        const float bb = bias[n0 + wn + n * 16 + l15];
        const f32x4 av = mode ? a1[m][n] : a0[m][n];
#pragma unroll
        for (int r = 0; r < 4; ++r)
          lw[(m * 16 + (g << 2) + r) * 32 + n * 16 + l15] =
              f2bf((av[r] + bb) * sc);
      }
    WAITLGKM();
    SCHEDB();
#pragma unroll
    for (int it = 0; it < 4; ++it) {
      const int rr = (lane >> 2) + it * 16;
      const int ck = (lane & 3) * 8;
      uint4 v = *reinterpret_cast<const uint4*>(&lw[rr * 32 + ck]);
      *reinterpret_cast<uint4*>(
          &dst[(((b << 4) + h) * 2048 + tb0 + rr) * 64 + hd0 + ck]) = v;
    }
  }

  // V^T: lw[32 hd][64 t]
  WAITLGKM();
#pragma unroll
  for (int m = 0; m < 4; ++m)
#pragma unroll
    for (int n = 0; n < 2; ++n) {
      const float bb = bv[n0 + wn + n * 16 + l15];
      uint2 w;
      w.x = cvtpk(a2[m][n][0] + bb, a2[m][n][1] + bb);
      w.y = cvtpk(a2[m][n][2] + bb, a2[m][n][3] + bb);
      *reinterpret_cast<uint2*>(&lw[(n * 16 + l15) * 64 + m * 16 + (g << 2)]) =
          w;
    }
  WAITLGKM();
  SCHEDB();
#pragma unroll
  for (int it = 0; it < 4; ++it) {
    const int hdr = (lane >> 3) + it * 8;
    const int ck = (lane & 7) * 8;
    uint4 v = *reinterpret_cast<const uint4*>(&lw[hdr * 64 + ck]);
    *reinterpret_cast<uint4*>(
        &Vo[(((b << 4) + h) * 64 + hd0 + hdr) * 2048 + tb0 + ck]) = v;
  }
}

// ---------------- output projection (128x64 tiles, fp32 out + bias) ------
// grid: 512 1-D. xcd = (y&3)*2 + (x&1). (r10 version)
__global__ __launch_bounds__(256) void k_gemm_out(
    const unsigned short* __restrict__ Ctx, const unsigned short* __restrict__ Wo,
    const float* __restrict__ bo, float* __restrict__ Out) {
  __shared__ unsigned short ls[16384];
  unsigned short* la0 = ls;
  unsigned short* lb0 = ls + 8192;
  const int id = blockIdx.x;
  const int xcd = id & 7, s4 = id >> 3;            // s4: 0..63
  const int bx = ((s4 >> 3) & 7) * 2 + (xcd & 1);  // 0..15
  const int by = (s4 & 7) * 4 + (xcd >> 1);        // 0..31
  const int tid = threadIdx.x;
  const int lane = tid & 63, wave = tid >> 6;
  const int l15 = lane & 15, g = lane >> 4;
  const int m0 = by * 128, n0 = bx * 64;
  const int wm = (wave >> 1) * 64, wn = (wave & 1) * 32;
  const int g16 = (g << 4);
  const int sx = (lane & 3) << 4;
  f32x4 acc[4][2] = {};

#define STG_OUT(buf, k0)                                                     \
  {                                                                          \
    _Pragma("unroll") for (int i = 0; i < 2; ++i) {                          \
      const int c = i * 256 + tid;                                           \
      const int row = c >> 2;                                                \
      const int scb = (((c & 3) << 4)) ^ ((row & 3) << 4);                   \
      gload16(Ctx + (m0 + row) * 1024 + (k0) + (scb >> 1),                   \
              (unsigned short*)((char*)(la0 + (buf)*4096) + c * 16));        \
    }                                                                        \
    {                                                                        \
      const int row = tid >> 2;                                              \
      const int scb = (((tid & 3) << 4)) ^ ((row & 3) << 4);                 \
      gload16(Wo + (n0 + row) * 1024 + (k0) + (scb >> 1),                    \
              (unsigned short*)((char*)(lb0 + (buf)*2048) + tid * 16));      \
    }                                                                        \
  }

  STG_OUT(0, 0);
  __syncthreads();

  for (int kt = 0; kt < 32; ++kt) {
    const int cur = kt & 1;
    unsigned short* la = la0 + cur * 4096;
    unsigned short* lb = lb0 + cur * 2048;
    if (kt + 1 < 32) STG_OUT(cur ^ 1, (kt + 1) * 32);
    bf16x8 af[4], bfr[2];
#pragma unroll
    for (int m = 0; m < 4; ++m)
      af[m] = *reinterpret_cast<const bf16x8*>(
          (char*)la + (wm + m * 16 + l15) * 64 + (g16 ^ sx));
#pragma unroll
    for (int n = 0; n < 2; ++n)
      bfr[n] = *reinterpret_cast<const bf16x8*>(
          (char*)lb + (wn + n * 16 + l15) * 64 + (g16 ^ sx));
#pragma unroll
    for (int m = 0; m < 4; ++m)
#pragma unroll
      for (int n = 0; n < 2; ++n)
        acc[m][n] = mfma16(af[m], bfr[n], acc[m][n]);
    __syncthreads();
  }
#undef STG_OUT

  float* lwf = (float*)(ls + wave * 4096);
#pragma unroll
  for (int m = 0; m < 4; ++m)
#pragma unroll
    for (int n = 0; n < 2; ++n) {
      const float bb = bo[n0 + wn + n * 16 + l15];
#pragma unroll
      for (int r = 0; r < 4; ++r)
        lwf[(m * 16 + (g << 2) + r) * 32 + n * 16 + l15] = acc[m][n][r] + bb;
    }
  WAITLGKM();
  SCHEDB();
#pragma unroll
  for (int it = 0; it < 8; ++it) {
    const int rr = (lane >> 3) + it * 8;
    const int ck = (lane & 7) * 4;
    float4 v = *reinterpret_cast<const float4*>(&lwf[rr * 32 + ck]);
    *reinterpret_cast<float4*>(&Out[(m0 + wm + rr) * 1024 + n0 + wn + ck]) = v;
  }
}

// ---------------- causal flash attention (8-wave split-pair, KVBLK=128) --
// (r13 structure, unchanged)

DEV void attn_stage128(const unsigned short* __restrict__ Kb,
                       const unsigned short* __restrict__ Vb,
                       unsigned short* lk, unsigned short* lv, int kv0,
                       int tid) {
#pragma unroll
  for (int i = 0; i < 2; ++i) {
    const int c = i * 512 + tid;            // 0..1023 chunks of 16B
    const int krow = c >> 3;                // 0..127
    const int kscb = ((c & 7) << 4) ^ ((krow & 7) << 4);
    gload16(Kb + (kv0 + krow) * 64 + (kscb >> 1),
            (unsigned short*)((char*)lk + c * 16));
    const int vrow = c >> 4;                // hd 0..63
    const int vscb = ((c & 15) << 4) ^ ((vrow & 7) << 4);
    gload16(Vb + vrow * 2048 + kv0 + (vscb >> 1),
            (unsigned short*)((char*)lv + c * 16));
  }
}

DEV void attn_step(const unsigned short* lk128, int s,
                   const unsigned short* lv128,
                   unsigned short (&lp)[16][64], const bf16x8 (&qf)[2],
                   f32x4 (&o)[4], float& lsum, int lane, int qloc, bool diag) {
  const int g = lane >> 4;
  const int l15 = lane & 15;
  f32x4 st[4];
  PRIO(1);
#pragma unroll
  for (int n = 0; n < 4; ++n) {
    f32x4 z = {};
    const int row = n * 16 + l15;
    const int sw = (row & 7) << 4;
#pragma unroll
    for (int kk = 0; kk < 2; ++kk) {
      bf16x8 kf = *reinterpret_cast<const bf16x8*>(
          (char*)lk128 + (s * 64 + row) * 128 + ((kk * 64 + (g << 4)) ^ sw));
      z = mfma16(kf, qf[kk], z);
    }
    st[n] = z;
  }
  PRIO(0);
  if (diag) {
#pragma unroll
    for (int n = 0; n < 4; ++n)
#pragma unroll
      for (int r = 0; r < 4; ++r)
        if (n * 16 + g * 4 + r > qloc) st[n][r] = -1e30f;
  }
  float rs = 0.f;
#pragma unroll
  for (int n = 0; n < 4; ++n)
#pragma unroll
    for (int r = 0; r < 4; ++r) {
      float p = exp2f(st[n][r]);
      st[n][r] = p;
      rs += p;
    }
  lsum += rs;
  const int psw = (l15 & 7) << 4;
#pragma unroll
  for (int n = 0; n < 4; ++n) {
    uint2 w;
    w.x = cvtpk(st[n][0], st[n][1]);
    w.y = cvtpk(st[n][2], st[n][3]);
    *reinterpret_cast<uint2*>(
        (char*)lp + l15 * 128 + (((n << 5) | (g << 3)) ^ psw)) = w;
  }
  WAITLGKM();
  SCHEDB();
  bf16x8 pb[2];
  pb[0] = *reinterpret_cast<const bf16x8*>(
      (char*)lp + l15 * 128 + (((g << 4)) ^ psw));
  pb[1] = *reinterpret_cast<const bf16x8*>(
      (char*)lp + l15 * 128 + ((64 + (g << 4)) ^ psw));
  PRIO(1);
#pragma unroll
  for (int h = 0; h < 4; ++h) {
    const int vr = h * 16 + l15;
    const int sw = (vr & 7) << 4;
#pragma unroll
    for (int kk = 0; kk < 2; ++kk) {
      bf16x8 vf = *reinterpret_cast<const bf16x8*>(
          (char*)lv128 + vr * 256 + ((s * 128 + kk * 64 + (g << 4)) ^ sw));
      o[h] = mfma16(vf, pb[kk], o[h]);
    }
  }
  PRIO(0);
}

DEV void attn_epi(unsigned short* __restrict__ Ctx,
                  unsigned short (&lp)[16][64], const f32x4 (&o)[4],
                  float lsum, int b, int hh, int qbase, int lane) {
  float lt = lsum;
  lt += __shfl_xor(lt, 16);
  lt += __shfl_xor(lt, 32);
  const float inv = 1.f / lt;
  const int g = lane >> 4;
  const int l15 = lane & 15;
  const int psw = (l15 & 7) << 4;
#pragma unroll
  for (int h = 0; h < 4; ++h) {
    uint2 w;
    w.x = cvtpk(o[h][0] * inv, o[h][1] * inv);
    w.y = cvtpk(o[h][2] * inv, o[h][3] * inv);
    *reinterpret_cast<uint2*>(
        (char*)lp + l15 * 128 + (((h << 5) | (g << 3)) ^ psw)) = w;
  }
  WAITLGKM();
  SCHEDB();
#pragma unroll
  for (int it = 0; it < 2; ++it) {
    const int q = (lane >> 3) + it * 8;
    const int blk = (lane & 7) ^ (q & 7);
    uint4 v = *reinterpret_cast<const uint4*>((char*)lp + q * 128 + blk * 16);
    *reinterpret_cast<uint4*>(
        &Ctx[(b * 2048 + qbase + q) * 1024 + hh * 64 + ((lane & 7) << 3)]) = v;
  }
}

__global__ __launch_bounds__(512) void k_attn(
    const unsigned short* __restrict__ Q, const unsigned short* __restrict__ K,
    const unsigned short* __restrict__ Vt, unsigned short* __restrict__ Ctx) {
  __shared__ unsigned short lk[2][8192];    // K [128][64], double buffer
  __shared__ unsigned short lv[2][8192];    // V^T [64][128], double buffer
  __shared__ unsigned short lp[8][16][64];  // per-wave, XOR-swizzled

  const int tid = threadIdx.x, lane = tid & 63, wave = tid >> 6;
  const int id = blockIdx.x;
  const int xcd = id & 7, r4 = id >> 3;  // r4: 0..63
  const int ip = r4 & 15;
  const int bh = ((r4 >> 4) << 3) + xcd;

  const int qtA = ip;
  const int qtB = 31 - ip;
  const int nb = (qtB >> 1) + 1;

  const bool isB = wave < 4;
  const int wv4 = wave & 3;
  const int qt = isB ? qtB : qtA;

  const unsigned short* Kb = K + bh * 2048 * 64;
  const unsigned short* Vb = Vt + bh * 64 * 2048;

  bf16x8 qf[2];
  {
    const unsigned short* qr =
        Q + (bh * 2048 + qt * 64 + wv4 * 16 + (lane & 15)) * 64 +
        ((lane >> 4) << 3);
    qf[0] = *reinterpret_cast<const bf16x8*>(qr);
    qf[1] = *reinterpret_cast<const bf16x8*>(qr + 32);
  }

  f32x4 o[4] = {};
  float lsum = 0.f;
  const int qloc = wv4 * 16 + (lane & 15);

  attn_stage128(Kb, Vb, lk[0], lv[0], 0, tid);

  for (int t = 0; t < nb; ++t) {
    WAITVM(0);
    BAR();
    {
      const int nx = (t + 1 < nb) ? t + 1 : nb - 1;
      attn_stage128(Kb, Vb, lk[(t + 1) & 1], lv[(t + 1) & 1], nx * 128, tid);
    }
    SCHEDB();
    const unsigned short* lkc = lk[t & 1];
    const unsigned short* lvc = lv[t & 1];
#pragma unroll
    for (int s = 0; s < 2; ++s) {
      const int sub = 2 * t + s;
      if (sub <= qt)
        attn_step(lkc, s, lvc, lp[wave], qf, o, lsum, lane, qloc, sub == qt);
    }
  }

  WAITVM(0);  // drain DMA before endpgm (LDS reallocation hazard)

  const int b = bh >> 4, hh = bh & 15;
  attn_epi(Ctx, lp[wave], o, lsum, b, hh, qt * 64 + wv4 * 16, lane);
}

// ---------------- launch ----------------
extern "C" void kernel_launch(void* const* d_in, const int* in_sizes, int n_in,
                              void* d_out, int out_size, void* d_ws,
                              size_t ws_size, hipStream_t stream) {
  const float* x = (const float*)d_in[0];
  const float* Wq = (const float*)d_in[1];
  const float* bq = (const float*)d_in[2];
  const float* Wk = (const float*)d_in[3];
  const float* bk = (const float*)d_in[4];
  const float* Wv = (const float*)d_in[5];
  const float* bv = (const float*)d_in[6];
  const float* Wo = (const float*)d_in[7];
  const float* bo = (const float*)d_in[8];
  float* out = (float*)d_out;

  char* ws = (char*)d_ws;
  unsigned short* xb = (unsigned short*)(ws);                    // 8 MB
  unsigned short* wqb = (unsigned short*)(ws + (8u << 20));      // 2 MB
  unsigned short* wkb = (unsigned short*)(ws + (10u << 20));
  unsigned short* wvb = (unsigned short*)(ws + (12u << 20));
  unsigned short* wob = (unsigned short*)(ws + (14u << 20));
  unsigned short* Qb = (unsigned short*)(ws + (16u << 20));      // 8 MB
  unsigned short* Kb = (unsigned short*)(ws + (24u << 20));      // 8 MB
  unsigned short* Vtb = (unsigned short*)(ws + (32u << 20));     // 8 MB
  unsigned short* Ctx = (unsigned short*)(ws + (40u << 20));     // 8 MB

  k_cvt_all<<<8192, 256, 0, stream>>>(x, Wq, Wk, Wv, Wo, xb);

  k_gemm_qkv<<<512, 256, 0, stream>>>(xb, wqb, wkb, wvb, bq, bk, bv,
                                      Qb, Kb, Vtb);
  k_attn<<<512, 512, 0, stream>>>(Qb, Kb, Vtb, Ctx);
  k_gemm_out<<<512, 256, 0, stream>>>(Ctx, wob, bo, out);
}